// Round 2
// baseline (308.971 us; speedup 1.0000x reference)
//
#include <hip/hip_runtime.h>
#include <math.h>

// Problem constants
constexpr int Bc = 8;
constexpr int Lc = 1024;
constexpr int Dc = 512;        // model dim
constexpr int Hc = 8;
constexpr int DHc = 64;
constexpr int DLc = 64;
constexpr int NBc = 128;
constexpr int TOTAL_OUT = 2 * DLc * Hc + 2 * DHc * Hc;  // 2048
constexpr int ROWS = Bc * Lc;  // 8192

using f32x4 = __attribute__((ext_vector_type(4))) float;
using s16x8 = __attribute__((ext_vector_type(8))) short;

__device__ __forceinline__ float bf2f(ushort u) {
    union { unsigned int i; float f; } v; v.i = ((unsigned int)u) << 16; return v.f;
}
__device__ __forceinline__ ushort f2bf(float f) {
    union { float f; unsigned int i; } v; v.f = f;
    unsigned int r = v.i + 0x7fffu + ((v.i >> 16) & 1u);  // RNE
    return (ushort)(r >> 16);
}
__device__ __forceinline__ float silu(float x) { return x / (1.0f + __expf(-x)); }

// ---------------------------------------------------------------------------
// Transpose + cast fp32 (R x C) -> bf16 (C x R)
// ---------------------------------------------------------------------------
__global__ __launch_bounds__(256) void transpose_cast(const float* __restrict__ in,
                                                      ushort* __restrict__ out,
                                                      int R, int C) {
    __shared__ float tile[32][33];
    int bc = blockIdx.x * 32, br = blockIdx.y * 32;
    int tx = threadIdx.x & 31, ty = threadIdx.x >> 5;  // 32x8
    for (int i = ty; i < 32; i += 8) {
        int r = br + i, c = bc + tx;
        tile[i][tx] = (r < R && c < C) ? in[(size_t)r * C + c] : 0.f;
    }
    __syncthreads();
    for (int i = ty; i < 32; i += 8) {
        int c = bc + i, r = br + tx;
        if (c < C && r < R) out[(size_t)c * R + r] = f2bf(tile[tx][i]);
    }
}

// ---------------------------------------------------------------------------
// LN1: x (ROWS x 512 fp32) -> bf16 normalized. One wave per row.
// ---------------------------------------------------------------------------
__global__ __launch_bounds__(256) void ln1_kernel(const float* __restrict__ x,
                                                  const float* __restrict__ g,
                                                  const float* __restrict__ bta,
                                                  ushort* __restrict__ outp) {
    int wid = threadIdx.x >> 6, lane = threadIdx.x & 63;
    int row = blockIdx.x * 4 + wid;
    const float4* xr = (const float4*)(x + (size_t)row * Dc);
    float4 a = xr[lane * 2], c = xr[lane * 2 + 1];
    float xv[8] = {a.x, a.y, a.z, a.w, c.x, c.y, c.z, c.w};
    float s = 0.f, q = 0.f;
#pragma unroll
    for (int i = 0; i < 8; i++) { s += xv[i]; q += xv[i] * xv[i]; }
#pragma unroll
    for (int off = 32; off; off >>= 1) { s += __shfl_xor(s, off); q += __shfl_xor(q, off); }
    float mean = s * (1.f / 512.f);
    float var  = q * (1.f / 512.f) - mean * mean;
    float rstd = rsqrtf(var + 1e-6f);
    const float4* gv = (const float4*)g; const float4* bv = (const float4*)bta;
    float4 g0 = gv[lane * 2], g1 = gv[lane * 2 + 1];
    float4 b0 = bv[lane * 2], b1 = bv[lane * 2 + 1];
    float G[8] = {g0.x, g0.y, g0.z, g0.w, g1.x, g1.y, g1.z, g1.w};
    float Bv[8] = {b0.x, b0.y, b0.z, b0.w, b1.x, b1.y, b1.z, b1.w};
    union { ushort u16[8]; uint4 v; } pk;
#pragma unroll
    for (int i = 0; i < 8; i++) pk.u16[i] = f2bf((xv[i] - mean) * rstd * G[i] + Bv[i]);
    ((uint4*)(outp + (size_t)row * Dc))[lane] = pk.v;
}

// ---------------------------------------------------------------------------
// GEMM1: X1 (8192x512 bf16) @ W1T^T (W1T is 2048x512 bf16, N-major) -> silu ->
// split-store u/v/q/k (each 8192x512 bf16).
// 128x128 tile, BK=64, 4 waves (2x2), per-wave 64x64.
// ---------------------------------------------------------------------------
__global__ __launch_bounds__(256) void gemm1_kernel(const ushort* __restrict__ A,
                                                    const ushort* __restrict__ Bt,
                                                    ushort* __restrict__ Ub,
                                                    ushort* __restrict__ Vb,
                                                    ushort* __restrict__ Qb,
                                                    ushort* __restrict__ Kb) {
    __shared__ __align__(16) ushort As[128][72];
    __shared__ __align__(16) ushort Bs[128][72];
    int tid = threadIdx.x;
    int m0 = blockIdx.x * 128, n0 = blockIdx.y * 128;
    int w = tid >> 6, lane = tid & 63;
    int wm = (w >> 1) * 64, wn = (w & 1) * 64;
    f32x4 acc[4][4] = {};
    for (int k0 = 0; k0 < Dc; k0 += 64) {
        __syncthreads();
#pragma unroll
        for (int c = tid; c < 1024; c += 256) {
            int r = c >> 3, c8 = c & 7;
            *(uint4*)&As[r][c8 * 8] = *(const uint4*)&A[(size_t)(m0 + r) * Dc + k0 + c8 * 8];
            *(uint4*)&Bs[r][c8 * 8] = *(const uint4*)&Bt[(size_t)(n0 + r) * Dc + k0 + c8 * 8];
        }
        __syncthreads();
#pragma unroll
        for (int ks = 0; ks < 2; ++ks) {
            int kb = ks * 32 + (lane >> 4) * 8;
            s16x8 af[4], bfr[4];
#pragma unroll
            for (int i = 0; i < 4; i++) af[i] = *(const s16x8*)&As[wm + i * 16 + (lane & 15)][kb];
#pragma unroll
            for (int j = 0; j < 4; j++) bfr[j] = *(const s16x8*)&Bs[wn + j * 16 + (lane & 15)][kb];
#pragma unroll
            for (int i = 0; i < 4; i++)
#pragma unroll
                for (int j = 0; j < 4; j++)
                    acc[i][j] = __builtin_amdgcn_mfma_f32_16x16x32_bf16(af[i], bfr[j], acc[i][j], 0, 0, 0);
        }
    }
    int lr = (lane >> 4) * 4, lc = lane & 15;
#pragma unroll
    for (int i = 0; i < 4; i++)
#pragma unroll
        for (int j = 0; j < 4; j++) {
            int col = n0 + wn + j * 16 + lc;
            int sect = col >> 9, cc = col & 511;
            ushort* dst = (sect == 0) ? Ub : (sect == 1) ? Vb : (sect == 2) ? Qb : Kb;
#pragma unroll
            for (int r = 0; r < 4; r++) {
                int row = m0 + wm + i * 16 + lr + r;
                dst[(size_t)row * 512 + cc] = f2bf(silu(acc[i][j][r]));
            }
        }
}

// ---------------------------------------------------------------------------
// Fused causal attention with rel-bias + silu scoring.
// Block: (mt, h, b). 128 M-rows per block, N-tiles of 64. 4 waves, each 32 M-rows.
// ---------------------------------------------------------------------------
__global__ __launch_bounds__(256) void attn_kernel(const ushort* __restrict__ Qb,
                                                   const ushort* __restrict__ Kb,
                                                   const ushort* __restrict__ Vb,
                                                   const int* __restrict__ ts,
                                                   const float* __restrict__ pos_w,
                                                   const float* __restrict__ ts_w,
                                                   ushort* __restrict__ Ob) {
    int mt = blockIdx.x, h = blockIdx.y, b = blockIdx.z;
    __shared__ __align__(16) ushort Qs[128][72];
    __shared__ __align__(16) ushort Ks[64][72];
    __shared__ __align__(16) ushort VTs[64][72];
    __shared__ __align__(16) ushort Ps[128][72];
    __shared__ float tsw[NBc + 1];
    int tid = threadIdx.x, w = tid >> 6, lane = tid & 63;
    const size_t hbase = ((size_t)b * Lc) * 512 + h * 64;
    // stage Q tile (128 x 64)
#pragma unroll
    for (int c = tid; c < 1024; c += 256) {
        int r = c >> 3, c8 = c & 7;
        *(uint4*)&Qs[r][c8 * 8] = *(const uint4*)&Qb[hbase + (size_t)(mt * 128 + r) * 512 + c8 * 8];
    }
    if (tid < NBc + 1) tsw[tid] = ts_w[tid];
    const int* tsb = ts + b * Lc;
    f32x4 acc_o[2][4] = {};
    int lr = (lane >> 4) * 4, lc = lane & 15;
    int ntiles = 2 * mt + 2;
    for (int nt = 0; nt < ntiles; ++nt) {
        int n0 = nt * 64;
        __syncthreads();  // protect Ks/VTs from previous iteration (and Qs/tsw on first)
#pragma unroll
        for (int c = tid; c < 512; c += 256) {
            int r = c >> 3, c8 = c & 7;
            *(uint4*)&Ks[r][c8 * 8] = *(const uint4*)&Kb[hbase + (size_t)(n0 + r) * 512 + c8 * 8];
            uint4 vv = *(const uint4*)&Vb[hbase + (size_t)(n0 + r) * 512 + c8 * 8];
            ushort* pv = (ushort*)&vv;
#pragma unroll
            for (int e = 0; e < 8; e++) VTs[c8 * 8 + e][r] = pv[e];  // transpose V
        }
        __syncthreads();
        // S = Q K^T for this wave's 32 rows x 64 cols
        f32x4 s[2][4] = {};
#pragma unroll
        for (int ks = 0; ks < 2; ++ks) {
            int kb = ks * 32 + (lane >> 4) * 8;
            s16x8 af[2], bfr[4];
#pragma unroll
            for (int i = 0; i < 2; i++) af[i] = *(const s16x8*)&Qs[w * 32 + i * 16 + (lane & 15)][kb];
#pragma unroll
            for (int j = 0; j < 4; j++) bfr[j] = *(const s16x8*)&Ks[j * 16 + (lane & 15)][kb];
#pragma unroll
            for (int i = 0; i < 2; i++)
#pragma unroll
                for (int j = 0; j < 4; j++)
                    s[i][j] = __builtin_amdgcn_mfma_f32_16x16x32_bf16(af[i], bfr[j], s[i][j], 0, 0, 0);
        }
        // bias + silu + mask -> P (bf16 in LDS, same-wave rows only)
#pragma unroll
        for (int i = 0; i < 2; i++) {
            int mbase = mt * 128 + w * 32 + i * 16 + lr;
            int me_r[4];
#pragma unroll
            for (int r = 0; r < 4; r++) {
                int mp = mbase + r + 1;
                me_r[r] = tsb[mp < Lc ? mp : (Lc - 1)];
            }
#pragma unroll
            for (int j = 0; j < 4; j++) {
                int ncol = n0 + j * 16 + lc;
                int tn = tsb[ncol];
#pragma unroll
                for (int r = 0; r < 4; r++) {
                    int m = mbase + r;
                    float val = 0.f;
                    if (ncol <= m) {
                        float mag = fmaxf(fabsf((float)(me_r[r] - tn)), 1.f);
                        int bkt = (int)(logf(mag) * (1.0f / 0.301f));
                        bkt = bkt < 0 ? 0 : (bkt > NBc ? NBc : bkt);
                        float sv = s[i][j][r] + pos_w[(Lc - 1) + ncol - m] + tsw[bkt];
                        val = silu(sv) * (1.f / (float)Lc);
                    }
                    Ps[w * 32 + i * 16 + lr + r][j * 16 + lc] = f2bf(val);
                }
            }
        }
        // O += P V  (A from own Ps rows, B from VTs)
#pragma unroll
        for (int ks = 0; ks < 2; ++ks) {
            int kb = ks * 32 + (lane >> 4) * 8;
            s16x8 pa[2], vb[4];
#pragma unroll
            for (int i = 0; i < 2; i++) pa[i] = *(const s16x8*)&Ps[w * 32 + i * 16 + (lane & 15)][kb];
#pragma unroll
            for (int j = 0; j < 4; j++) vb[j] = *(const s16x8*)&VTs[j * 16 + (lane & 15)][kb];
#pragma unroll
            for (int i = 0; i < 2; i++)
#pragma unroll
                for (int j = 0; j < 4; j++)
                    acc_o[i][j] = __builtin_amdgcn_mfma_f32_16x16x32_bf16(pa[i], vb[j], acc_o[i][j], 0, 0, 0);
        }
    }
#pragma unroll
    for (int i = 0; i < 2; i++)
#pragma unroll
        for (int j = 0; j < 4; j++)
#pragma unroll
            for (int r = 0; r < 4; r++) {
                int m = mt * 128 + w * 32 + i * 16 + lr + r;
                Ob[hbase + (size_t)m * 512 + j * 16 + lc] = f2bf(acc_o[i][j][r]);
            }
}

// ---------------------------------------------------------------------------
// LN2(attn) * u -> bf16. One wave per row.
// ---------------------------------------------------------------------------
__global__ __launch_bounds__(256) void ln2_kernel(const ushort* __restrict__ z,
                                                  const ushort* __restrict__ u,
                                                  const float* __restrict__ g,
                                                  const float* __restrict__ bta,
                                                  ushort* __restrict__ outp) {
    int wid = threadIdx.x >> 6, lane = threadIdx.x & 63;
    int row = blockIdx.x * 4 + wid;
    uint4 zv = ((const uint4*)(z + (size_t)row * 512))[lane];
    ushort* zu = (ushort*)&zv;
    float xv[8], s = 0.f, q = 0.f;
#pragma unroll
    for (int i = 0; i < 8; i++) { xv[i] = bf2f(zu[i]); s += xv[i]; q += xv[i] * xv[i]; }
#pragma unroll
    for (int off = 32; off; off >>= 1) { s += __shfl_xor(s, off); q += __shfl_xor(q, off); }
    float mean = s * (1.f / 512.f);
    float var  = q * (1.f / 512.f) - mean * mean;
    float rstd = rsqrtf(var + 1e-6f);
    uint4 uv = ((const uint4*)(u + (size_t)row * 512))[lane];
    ushort* uu = (ushort*)&uv;
    const float4* gv = (const float4*)g; const float4* bv = (const float4*)bta;
    float4 g0 = gv[lane * 2], g1 = gv[lane * 2 + 1];
    float4 b0 = bv[lane * 2], b1 = bv[lane * 2 + 1];
    float G[8] = {g0.x, g0.y, g0.z, g0.w, g1.x, g1.y, g1.z, g1.w};
    float Bv[8] = {b0.x, b0.y, b0.z, b0.w, b1.x, b1.y, b1.z, b1.w};
    union { ushort u16[8]; uint4 v; } pk;
#pragma unroll
    for (int i = 0; i < 8; i++)
        pk.u16[i] = f2bf(((xv[i] - mean) * rstd * G[i] + Bv[i]) * bf2f(uu[i]));
    ((uint4*)(outp + (size_t)row * 512))[lane] = pk.v;
}

// ---------------------------------------------------------------------------
// GEMM2: A2 (8192x512 bf16) @ W2T^T (W2T 512x512 bf16 N-major) + out_b + x -> fp32
// ---------------------------------------------------------------------------
__global__ __launch_bounds__(256) void gemm2_kernel(const ushort* __restrict__ A,
                                                    const ushort* __restrict__ Bt,
                                                    const float* __restrict__ ob,
                                                    const float* __restrict__ x,
                                                    float* __restrict__ outp) {
    __shared__ __align__(16) ushort As[128][72];
    __shared__ __align__(16) ushort Bs[128][72];
    int tid = threadIdx.x;
    int m0 = blockIdx.x * 128, n0 = blockIdx.y * 128;
    int w = tid >> 6, lane = tid & 63;
    int wm = (w >> 1) * 64, wn = (w & 1) * 64;
    f32x4 acc[4][4] = {};
    for (int k0 = 0; k0 < Dc; k0 += 64) {
        __syncthreads();
#pragma unroll
        for (int c = tid; c < 1024; c += 256) {
            int r = c >> 3, c8 = c & 7;
            *(uint4*)&As[r][c8 * 8] = *(const uint4*)&A[(size_t)(m0 + r) * Dc + k0 + c8 * 8];
            *(uint4*)&Bs[r][c8 * 8] = *(const uint4*)&Bt[(size_t)(n0 + r) * Dc + k0 + c8 * 8];
        }
        __syncthreads();
#pragma unroll
        for (int ks = 0; ks < 2; ++ks) {
            int kb = ks * 32 + (lane >> 4) * 8;
            s16x8 af[4], bfr[4];
#pragma unroll
            for (int i = 0; i < 4; i++) af[i] = *(const s16x8*)&As[wm + i * 16 + (lane & 15)][kb];
#pragma unroll
            for (int j = 0; j < 4; j++) bfr[j] = *(const s16x8*)&Bs[wn + j * 16 + (lane & 15)][kb];
#pragma unroll
            for (int i = 0; i < 4; i++)
#pragma unroll
                for (int j = 0; j < 4; j++)
                    acc[i][j] = __builtin_amdgcn_mfma_f32_16x16x32_bf16(af[i], bfr[j], acc[i][j], 0, 0, 0);
        }
    }
    int lr = (lane >> 4) * 4, lc = lane & 15;
#pragma unroll
    for (int i = 0; i < 4; i++)
#pragma unroll
        for (int j = 0; j < 4; j++) {
            int col = n0 + wn + j * 16 + lc;
            float bias = ob[col];
#pragma unroll
            for (int r = 0; r < 4; r++) {
                int row = m0 + wm + i * 16 + lr + r;
                size_t off = (size_t)row * 512 + col;
                outp[off] = acc[i][j][r] + bias + x[off];
            }
        }
}

// ---------------------------------------------------------------------------
extern "C" void kernel_launch(void* const* d_in, const int* in_sizes, int n_in,
                              void* d_out, int out_size, void* d_ws, size_t ws_size,
                              hipStream_t stream) {
    const float* x      = (const float*)d_in[0];
    const int*   tsp    = (const int*)d_in[1];
    // d_in[2]: attn_mask (implicit causal; unused)
    const float* uvqk_w = (const float*)d_in[3];
    const float* out_w  = (const float*)d_in[4];
    const float* out_b  = (const float*)d_in[5];
    const float* ln1_g  = (const float*)d_in[6];
    const float* ln1_b  = (const float*)d_in[7];
    const float* ln2_g  = (const float*)d_in[8];
    const float* ln2_b  = (const float*)d_in[9];
    const float* ts_w   = (const float*)d_in[10];
    const float* pos_w  = (const float*)d_in[11];
    float* outp = (float*)d_out;

    char* ws = (char*)d_ws;
    size_t off = 0;
    auto alloc = [&](size_t bytes) { char* p = ws + off; off += (bytes + 255) & ~(size_t)255; return p; };
    const size_t MAT = (size_t)ROWS * 512 * sizeof(ushort);  // 8 MB
    ushort* W1T = (ushort*)alloc((size_t)TOTAL_OUT * Dc * 2);  // 2 MB
    ushort* W2T = (ushort*)alloc((size_t)Dc * Dc * 2);         // 0.5 MB
    ushort* X1  = (ushort*)alloc(MAT);
    ushort* Ub  = (ushort*)alloc(MAT);
    ushort* Vb  = (ushort*)alloc(MAT);
    ushort* Qb  = (ushort*)alloc(MAT);
    ushort* Kb  = (ushort*)alloc(MAT);
    ushort* Ob  = (ushort*)alloc(MAT);
    ushort* A2  = X1;  // X1 dead after gemm1 -> reuse for ln2 output

    transpose_cast<<<dim3(TOTAL_OUT / 32, Dc / 32), 256, 0, stream>>>(uvqk_w, W1T, Dc, TOTAL_OUT);
    transpose_cast<<<dim3(Dc / 32, Dc / 32), 256, 0, stream>>>(out_w, W2T, Dc, Dc);
    ln1_kernel<<<ROWS / 4, 256, 0, stream>>>(x, ln1_g, ln1_b, X1);
    gemm1_kernel<<<dim3(ROWS / 128, TOTAL_OUT / 128), 256, 0, stream>>>(X1, W1T, Ub, Vb, Qb, Kb);
    attn_kernel<<<dim3(Lc / 128, Hc, Bc), 256, 0, stream>>>(Qb, Kb, Vb, tsp, pos_w, ts_w, Ob);
    ln2_kernel<<<ROWS / 4, 256, 0, stream>>>(Ob, Ub, ln2_g, ln2_b, A2);
    gemm2_kernel<<<dim3(ROWS / 128, Dc / 128), 256, 0, stream>>>(A2, W2T, out_b, x, outp);
}

// Round 3
// 263.604 us; speedup vs baseline: 1.1721x; 1.1721x over previous
//
#include <hip/hip_runtime.h>
#include <math.h>

// Problem constants
constexpr int Bc = 8;
constexpr int Lc = 1024;
constexpr int Dc = 512;        // model dim
constexpr int Hc = 8;
constexpr int DHc = 64;
constexpr int DLc = 64;
constexpr int NBc = 128;
constexpr int TOTAL_OUT = 2 * DLc * Hc + 2 * DHc * Hc;  // 2048
constexpr int ROWS = Bc * Lc;  // 8192

using f32x4 = __attribute__((ext_vector_type(4))) float;
using s16x8 = __attribute__((ext_vector_type(8))) short;

__device__ __forceinline__ float bf2f(ushort u) {
    union { unsigned int i; float f; } v; v.i = ((unsigned int)u) << 16; return v.f;
}
__device__ __forceinline__ ushort f2bf(float f) {
    union { float f; unsigned int i; } v; v.f = f;
    unsigned int r = v.i + 0x7fffu + ((v.i >> 16) & 1u);  // RNE
    return (ushort)(r >> 16);
}
// silu via v_exp + v_rcp (1-instr transcendentals) instead of precise divide
__device__ __forceinline__ float silu(float x) {
    float e = __expf(-x);
    return x * __builtin_amdgcn_rcpf(1.0f + e);
}

// ---------------------------------------------------------------------------
// Transpose + cast fp32 (R x C) -> bf16 (C x R)
// ---------------------------------------------------------------------------
__global__ __launch_bounds__(256) void transpose_cast(const float* __restrict__ in,
                                                      ushort* __restrict__ out,
                                                      int R, int C) {
    __shared__ float tile[32][33];
    int bc = blockIdx.x * 32, br = blockIdx.y * 32;
    int tx = threadIdx.x & 31, ty = threadIdx.x >> 5;  // 32x8
    for (int i = ty; i < 32; i += 8) {
        int r = br + i, c = bc + tx;
        tile[i][tx] = (r < R && c < C) ? in[(size_t)r * C + c] : 0.f;
    }
    __syncthreads();
    for (int i = ty; i < 32; i += 8) {
        int c = bc + i, r = br + tx;
        if (c < C && r < R) out[(size_t)c * R + r] = f2bf(tile[tx][i]);
    }
}

// ---------------------------------------------------------------------------
// LN1: x (ROWS x 512 fp32) -> bf16 normalized. One wave per row.
// ---------------------------------------------------------------------------
__global__ __launch_bounds__(256) void ln1_kernel(const float* __restrict__ x,
                                                  const float* __restrict__ g,
                                                  const float* __restrict__ bta,
                                                  ushort* __restrict__ outp) {
    int wid = threadIdx.x >> 6, lane = threadIdx.x & 63;
    int row = blockIdx.x * 4 + wid;
    const float4* xr = (const float4*)(x + (size_t)row * Dc);
    float4 a = xr[lane * 2], c = xr[lane * 2 + 1];
    float xv[8] = {a.x, a.y, a.z, a.w, c.x, c.y, c.z, c.w};
    float s = 0.f, q = 0.f;
#pragma unroll
    for (int i = 0; i < 8; i++) { s += xv[i]; q += xv[i] * xv[i]; }
#pragma unroll
    for (int off = 32; off; off >>= 1) { s += __shfl_xor(s, off); q += __shfl_xor(q, off); }
    float mean = s * (1.f / 512.f);
    float var  = q * (1.f / 512.f) - mean * mean;
    float rstd = rsqrtf(var + 1e-6f);
    const float4* gv = (const float4*)g; const float4* bv = (const float4*)bta;
    float4 g0 = gv[lane * 2], g1 = gv[lane * 2 + 1];
    float4 b0 = bv[lane * 2], b1 = bv[lane * 2 + 1];
    float G[8] = {g0.x, g0.y, g0.z, g0.w, g1.x, g1.y, g1.z, g1.w};
    float Bv[8] = {b0.x, b0.y, b0.z, b0.w, b1.x, b1.y, b1.z, b1.w};
    union { ushort u16[8]; uint4 v; } pk;
#pragma unroll
    for (int i = 0; i < 8; i++) pk.u16[i] = f2bf((xv[i] - mean) * rstd * G[i] + Bv[i]);
    ((uint4*)(outp + (size_t)row * Dc))[lane] = pk.v;
}

// ---------------------------------------------------------------------------
// GEMM1: X1 (8192x512 bf16) @ W1T^T (W1T is 2048x512 bf16, N-major) -> silu ->
// split-store u/v/q/k (each 8192x512 bf16).
// ---------------------------------------------------------------------------
__global__ __launch_bounds__(256) void gemm1_kernel(const ushort* __restrict__ A,
                                                    const ushort* __restrict__ Bt,
                                                    ushort* __restrict__ Ub,
                                                    ushort* __restrict__ Vb,
                                                    ushort* __restrict__ Qb,
                                                    ushort* __restrict__ Kb) {
    __shared__ __align__(16) ushort As[128][72];
    __shared__ __align__(16) ushort Bs[128][72];
    int tid = threadIdx.x;
    int m0 = blockIdx.x * 128, n0 = blockIdx.y * 128;
    int w = tid >> 6, lane = tid & 63;
    int wm = (w >> 1) * 64, wn = (w & 1) * 64;
    f32x4 acc[4][4] = {};
    for (int k0 = 0; k0 < Dc; k0 += 64) {
        __syncthreads();
#pragma unroll
        for (int c = tid; c < 1024; c += 256) {
            int r = c >> 3, c8 = c & 7;
            *(uint4*)&As[r][c8 * 8] = *(const uint4*)&A[(size_t)(m0 + r) * Dc + k0 + c8 * 8];
            *(uint4*)&Bs[r][c8 * 8] = *(const uint4*)&Bt[(size_t)(n0 + r) * Dc + k0 + c8 * 8];
        }
        __syncthreads();
#pragma unroll
        for (int ks = 0; ks < 2; ++ks) {
            int kb = ks * 32 + (lane >> 4) * 8;
            s16x8 af[4], bfr[4];
#pragma unroll
            for (int i = 0; i < 4; i++) af[i] = *(const s16x8*)&As[wm + i * 16 + (lane & 15)][kb];
#pragma unroll
            for (int j = 0; j < 4; j++) bfr[j] = *(const s16x8*)&Bs[wn + j * 16 + (lane & 15)][kb];
#pragma unroll
            for (int i = 0; i < 4; i++)
#pragma unroll
                for (int j = 0; j < 4; j++)
                    acc[i][j] = __builtin_amdgcn_mfma_f32_16x16x32_bf16(af[i], bfr[j], acc[i][j], 0, 0, 0);
        }
    }
    int lr = (lane >> 4) * 4, lc = lane & 15;
#pragma unroll
    for (int i = 0; i < 4; i++)
#pragma unroll
        for (int j = 0; j < 4; j++) {
            int col = n0 + wn + j * 16 + lc;
            int sect = col >> 9, cc = col & 511;
            ushort* dst = (sect == 0) ? Ub : (sect == 1) ? Vb : (sect == 2) ? Qb : Kb;
#pragma unroll
            for (int r = 0; r < 4; r++) {
                int row = m0 + wm + i * 16 + lr + r;
                dst[(size_t)row * 512 + cc] = f2bf(silu(acc[i][j][r]));
            }
        }
}

// ---------------------------------------------------------------------------
// Fused causal attention with rel-bias + silu scoring.
// Block: (mt, h, b), LPT order (heavy mt first). 128 M-rows/block, N-tiles of 64.
// 4 waves, each 32 M-rows. Q fragments in registers; pos_w/ts_w in LDS.
// ---------------------------------------------------------------------------
__global__ __launch_bounds__(256) void attn_kernel(const ushort* __restrict__ Qb,
                                                   const ushort* __restrict__ Kb,
                                                   const ushort* __restrict__ Vb,
                                                   const int* __restrict__ ts,
                                                   const float* __restrict__ pos_w,
                                                   const float* __restrict__ ts_w,
                                                   ushort* __restrict__ Ob) {
    int mt = (gridDim.x - 1) - blockIdx.x;  // LPT: heaviest blocks dispatch first
    int h = blockIdx.y, b = blockIdx.z;
    __shared__ __align__(16) ushort Ks[64][72];
    __shared__ __align__(16) ushort VTs[64][72];
    __shared__ __align__(16) ushort Ps[128][72];
    __shared__ float tsw[NBc + 1];
    __shared__ float posw[2 * Lc - 1];
    int tid = threadIdx.x, w = tid >> 6, lane = tid & 63;
    const size_t hbase = ((size_t)b * Lc) * 512 + h * 64;
    const int m0 = mt * 128;
    // stage pos_w (8KB) + ts_w into LDS (first in-loop barrier protects readers)
    for (int i2 = tid; i2 < 2 * Lc - 1; i2 += 256) posw[i2] = pos_w[i2];
    if (tid < NBc + 1) tsw[tid] = ts_w[tid];
    // Q fragments: straight from global into registers, reused for all n-tiles
    s16x8 qf[2][2];
#pragma unroll
    for (int i = 0; i < 2; i++)
#pragma unroll
        for (int ks = 0; ks < 2; ++ks) {
            int kb = ks * 32 + (lane >> 4) * 8;
            qf[i][ks] = *(const s16x8*)&Qb[hbase + (size_t)(m0 + w * 32 + i * 16 + (lane & 15)) * 512 + kb];
        }
    const int* tsb = ts + b * Lc;
    f32x4 acc_o[2][4] = {};
    int lr = (lane >> 4) * 4, lc = lane & 15;
    int ntiles = 2 * mt + 2;
    for (int nt = 0; nt < ntiles; ++nt) {
        int n0 = nt * 64;
        __syncthreads();  // protect Ks/VTs (and posw/tsw on first iteration)
#pragma unroll
        for (int c = tid; c < 512; c += 256) {
            int r = c >> 3, c8 = c & 7;
            *(uint4*)&Ks[r][c8 * 8] = *(const uint4*)&Kb[hbase + (size_t)(n0 + r) * 512 + c8 * 8];
            uint4 vv = *(const uint4*)&Vb[hbase + (size_t)(n0 + r) * 512 + c8 * 8];
            ushort* pv = (ushort*)&vv;
#pragma unroll
            for (int e = 0; e < 8; e++) VTs[c8 * 8 + e][r] = pv[e];  // transpose V
        }
        __syncthreads();
        // S = Q K^T for this wave's 32 rows x 64 cols
        f32x4 s[2][4] = {};
#pragma unroll
        for (int ks = 0; ks < 2; ++ks) {
            int kb = ks * 32 + (lane >> 4) * 8;
            s16x8 bfr[4];
#pragma unroll
            for (int j = 0; j < 4; j++) bfr[j] = *(const s16x8*)&Ks[j * 16 + (lane & 15)][kb];
#pragma unroll
            for (int i = 0; i < 2; i++)
#pragma unroll
                for (int j = 0; j < 4; j++)
                    s[i][j] = __builtin_amdgcn_mfma_f32_16x16x32_bf16(qf[i][ks], bfr[j], s[i][j], 0, 0, 0);
        }
        // bias + silu + mask -> P (bf16 in LDS, same-wave rows only)
#pragma unroll
        for (int i = 0; i < 2; i++) {
            int mbase = m0 + w * 32 + i * 16 + lr;
            int me_r[4];
#pragma unroll
            for (int r = 0; r < 4; r++) {
                int mp = mbase + r + 1;
                me_r[r] = tsb[mp < Lc ? mp : (Lc - 1)];
            }
#pragma unroll
            for (int j = 0; j < 4; j++) {
                int ncol = n0 + j * 16 + lc;
                int tn = tsb[ncol];
#pragma unroll
                for (int r = 0; r < 4; r++) {
                    int m = mbase + r;
                    float val = 0.f;
                    if (ncol <= m) {
                        float mag = fmaxf(fabsf((float)(me_r[r] - tn)), 1.f);
                        // ln(mag)/0.301 == log2(mag) * (ln2/0.301)
                        int bkt = (int)(__log2f(mag) * 2.3028147f);
                        bkt = bkt < 0 ? 0 : (bkt > NBc ? NBc : bkt);
                        float sv = s[i][j][r] + posw[(Lc - 1) + ncol - m] + tsw[bkt];
                        val = silu(sv) * (1.f / (float)Lc);
                    }
                    Ps[w * 32 + i * 16 + lr + r][j * 16 + lc] = f2bf(val);
                }
            }
        }
        // O += P V  (A from own Ps rows, B from VTs)
#pragma unroll
        for (int ks = 0; ks < 2; ++ks) {
            int kb = ks * 32 + (lane >> 4) * 8;
            s16x8 pa[2], vb[4];
#pragma unroll
            for (int i = 0; i < 2; i++) pa[i] = *(const s16x8*)&Ps[w * 32 + i * 16 + (lane & 15)][kb];
#pragma unroll
            for (int j = 0; j < 4; j++) vb[j] = *(const s16x8*)&VTs[j * 16 + (lane & 15)][kb];
#pragma unroll
            for (int i = 0; i < 2; i++)
#pragma unroll
                for (int j = 0; j < 4; j++)
                    acc_o[i][j] = __builtin_amdgcn_mfma_f32_16x16x32_bf16(pa[i], vb[j], acc_o[i][j], 0, 0, 0);
        }
    }
#pragma unroll
    for (int i = 0; i < 2; i++)
#pragma unroll
        for (int j = 0; j < 4; j++)
#pragma unroll
            for (int r = 0; r < 4; r++) {
                int m = m0 + w * 32 + i * 16 + lr + r;
                Ob[hbase + (size_t)m * 512 + j * 16 + lc] = f2bf(acc_o[i][j][r]);
            }
}

// ---------------------------------------------------------------------------
// LN2(attn) * u -> bf16. One wave per row.
// ---------------------------------------------------------------------------
__global__ __launch_bounds__(256) void ln2_kernel(const ushort* __restrict__ z,
                                                  const ushort* __restrict__ u,
                                                  const float* __restrict__ g,
                                                  const float* __restrict__ bta,
                                                  ushort* __restrict__ outp) {
    int wid = threadIdx.x >> 6, lane = threadIdx.x & 63;
    int row = blockIdx.x * 4 + wid;
    uint4 zv = ((const uint4*)(z + (size_t)row * 512))[lane];
    ushort* zu = (ushort*)&zv;
    float xv[8], s = 0.f, q = 0.f;
#pragma unroll
    for (int i = 0; i < 8; i++) { xv[i] = bf2f(zu[i]); s += xv[i]; q += xv[i] * xv[i]; }
#pragma unroll
    for (int off = 32; off; off >>= 1) { s += __shfl_xor(s, off); q += __shfl_xor(q, off); }
    float mean = s * (1.f / 512.f);
    float var  = q * (1.f / 512.f) - mean * mean;
    float rstd = rsqrtf(var + 1e-6f);
    uint4 uv = ((const uint4*)(u + (size_t)row * 512))[lane];
    ushort* uu = (ushort*)&uv;
    const float4* gv = (const float4*)g; const float4* bv = (const float4*)bta;
    float4 g0 = gv[lane * 2], g1 = gv[lane * 2 + 1];
    float4 b0 = bv[lane * 2], b1 = bv[lane * 2 + 1];
    float G[8] = {g0.x, g0.y, g0.z, g0.w, g1.x, g1.y, g1.z, g1.w};
    float Bv[8] = {b0.x, b0.y, b0.z, b0.w, b1.x, b1.y, b1.z, b1.w};
    union { ushort u16[8]; uint4 v; } pk;
#pragma unroll
    for (int i = 0; i < 8; i++)
        pk.u16[i] = f2bf(((xv[i] - mean) * rstd * G[i] + Bv[i]) * bf2f(uu[i]));
    ((uint4*)(outp + (size_t)row * 512))[lane] = pk.v;
}

// ---------------------------------------------------------------------------
// GEMM2: A2 (8192x512 bf16) @ W2T^T (W2T 512x512 bf16 N-major) + out_b + x -> fp32
// ---------------------------------------------------------------------------
__global__ __launch_bounds__(256) void gemm2_kernel(const ushort* __restrict__ A,
                                                    const ushort* __restrict__ Bt,
                                                    const float* __restrict__ ob,
                                                    const float* __restrict__ x,
                                                    float* __restrict__ outp) {
    __shared__ __align__(16) ushort As[128][72];
    __shared__ __align__(16) ushort Bs[128][72];
    int tid = threadIdx.x;
    int m0 = blockIdx.x * 128, n0 = blockIdx.y * 128;
    int w = tid >> 6, lane = tid & 63;
    int wm = (w >> 1) * 64, wn = (w & 1) * 64;
    f32x4 acc[4][4] = {};
    for (int k0 = 0; k0 < Dc; k0 += 64) {
        __syncthreads();
#pragma unroll
        for (int c = tid; c < 1024; c += 256) {
            int r = c >> 3, c8 = c & 7;
            *(uint4*)&As[r][c8 * 8] = *(const uint4*)&A[(size_t)(m0 + r) * Dc + k0 + c8 * 8];
            *(uint4*)&Bs[r][c8 * 8] = *(const uint4*)&Bt[(size_t)(n0 + r) * Dc + k0 + c8 * 8];
        }
        __syncthreads();
#pragma unroll
        for (int ks = 0; ks < 2; ++ks) {
            int kb = ks * 32 + (lane >> 4) * 8;
            s16x8 af[4], bfr[4];
#pragma unroll
            for (int i = 0; i < 4; i++) af[i] = *(const s16x8*)&As[wm + i * 16 + (lane & 15)][kb];
#pragma unroll
            for (int j = 0; j < 4; j++) bfr[j] = *(const s16x8*)&Bs[wn + j * 16 + (lane & 15)][kb];
#pragma unroll
            for (int i = 0; i < 4; i++)
#pragma unroll
                for (int j = 0; j < 4; j++)
                    acc[i][j] = __builtin_amdgcn_mfma_f32_16x16x32_bf16(af[i], bfr[j], acc[i][j], 0, 0, 0);
        }
    }
    int lr = (lane >> 4) * 4, lc = lane & 15;
#pragma unroll
    for (int i = 0; i < 4; i++)
#pragma unroll
        for (int j = 0; j < 4; j++) {
            int col = n0 + wn + j * 16 + lc;
            float bias = ob[col];
#pragma unroll
            for (int r = 0; r < 4; r++) {
                int row = m0 + wm + i * 16 + lr + r;
                size_t off = (size_t)row * 512 + col;
                outp[off] = acc[i][j][r] + bias + x[off];
            }
        }
}

// ---------------------------------------------------------------------------
extern "C" void kernel_launch(void* const* d_in, const int* in_sizes, int n_in,
                              void* d_out, int out_size, void* d_ws, size_t ws_size,
                              hipStream_t stream) {
    const float* x      = (const float*)d_in[0];
    const int*   tsp    = (const int*)d_in[1];
    // d_in[2]: attn_mask (implicit causal; unused)
    const float* uvqk_w = (const float*)d_in[3];
    const float* out_w  = (const float*)d_in[4];
    const float* out_b  = (const float*)d_in[5];
    const float* ln1_g  = (const float*)d_in[6];
    const float* ln1_b  = (const float*)d_in[7];
    const float* ln2_g  = (const float*)d_in[8];
    const float* ln2_b  = (const float*)d_in[9];
    const float* ts_w   = (const float*)d_in[10];
    const float* pos_w  = (const float*)d_in[11];
    float* outp = (float*)d_out;

    char* ws = (char*)d_ws;
    size_t off = 0;
    auto alloc = [&](size_t bytes) { char* p = ws + off; off += (bytes + 255) & ~(size_t)255; return p; };
    const size_t MAT = (size_t)ROWS * 512 * sizeof(ushort);  // 8 MB
    ushort* W1T = (ushort*)alloc((size_t)TOTAL_OUT * Dc * 2);  // 2 MB
    ushort* W2T = (ushort*)alloc((size_t)Dc * Dc * 2);         // 0.5 MB
    ushort* X1  = (ushort*)alloc(MAT);
    ushort* Ub  = (ushort*)alloc(MAT);
    ushort* Vb  = (ushort*)alloc(MAT);
    ushort* Qb  = (ushort*)alloc(MAT);
    ushort* Kb  = (ushort*)alloc(MAT);
    ushort* Ob  = (ushort*)alloc(MAT);
    ushort* A2  = X1;  // X1 dead after gemm1 -> reuse for ln2 output

    transpose_cast<<<dim3(TOTAL_OUT / 32, Dc / 32), 256, 0, stream>>>(uvqk_w, W1T, Dc, TOTAL_OUT);
    transpose_cast<<<dim3(Dc / 32, Dc / 32), 256, 0, stream>>>(out_w, W2T, Dc, Dc);
    ln1_kernel<<<ROWS / 4, 256, 0, stream>>>(x, ln1_g, ln1_b, X1);
    gemm1_kernel<<<dim3(ROWS / 128, TOTAL_OUT / 128), 256, 0, stream>>>(X1, W1T, Ub, Vb, Qb, Kb);
    attn_kernel<<<dim3(Lc / 128, Hc, Bc), 256, 0, stream>>>(Qb, Kb, Vb, tsp, pos_w, ts_w, Ob);
    ln2_kernel<<<ROWS / 4, 256, 0, stream>>>(Ob, Ub, ln2_g, ln2_b, A2);
    gemm2_kernel<<<dim3(ROWS / 128, Dc / 128), 256, 0, stream>>>(A2, W2T, out_b, x, outp);
}